// Round 5
// baseline (448.280 us; speedup 1.0000x reference)
//
#include <hip/hip_runtime.h>

// Problem constants (fixed by setup_inputs)
#define BATCH    4
#define NQ       10000
#define EMB      256
#define NH       8
#define DH       32
#define NL       4
#define NP       8
#define S_TOTAL  19560
#define NROW     (BATCH * NQ)          // 40000
#define VROWS    (BATCH * S_TOTAL)     // 78240

typedef _Float16 half8 __attribute__((ext_vector_type(8)));
typedef _Float16 half4v __attribute__((ext_vector_type(4)));
typedef _Float16 half2v __attribute__((ext_vector_type(2)));
typedef float floatx4 __attribute__((ext_vector_type(4)));

// ---------------------------------------------------------------------------
// One-shot weight prep: transpose+swizzle all three weight matrices to f16.
// Logical row n (0..1023): [0,512) w_off -> wT768, [512,768) w_attn -> wT768,
// [768,1024) w_val (256 rows) -> wvaT. Swizzle: 16B chunk c of row n lands at
// chunk c ^ (n&7).
// ---------------------------------------------------------------------------
__global__ __launch_bounds__(256) void prep_weights(
    const float* __restrict__ w_off, const float* __restrict__ w_attn,
    const float* __restrict__ w_val, _Float16* __restrict__ wT768,
    _Float16* __restrict__ wvaT) {
  const int tid = blockIdx.x * 256 + threadIdx.x;   // over 1024*256
  const int n = tid >> 8, k = tid & 255;
  const int c = k >> 3, e = k & 7;
  const int swz = ((c ^ (n & 7)) << 3) + e;
  float v;
  _Float16* dst;
  if (n < 512)      { v = w_off[(size_t)k * 512 + n];          dst = wT768 + (size_t)n * 256; }
  else if (n < 768) { v = w_attn[(size_t)k * 256 + (n - 512)]; dst = wT768 + (size_t)n * 256; }
  else              { v = w_val[(size_t)k * 256 + (n - 768)];  dst = wvaT + (size_t)(n - 768) * 256; }
  dst[swz] = (_Float16)v;
}

// ---------------------------------------------------------------------------
// MFMA GEMM: A-register-resident + B-chunk-in-LDS, 3 blocks/CU.
//   C = A[M,256]_f32 @ WTs[NC,256]^T + bias(col-select)
// Register-prefetch double-buffer; SWZ path uses swapped-operand MFMA so the
// 4 acc regs land on 4 consecutive channels -> coalesced 8B half4 stores.
// (r3 verified correct; GEMM time is NOT the bottleneck — left as-is.)
// ---------------------------------------------------------------------------
template <int NC, int NYS, bool SWZ>
__global__ __launch_bounds__(256, 3) void gemm6(
    const float* __restrict__ A, const _Float16* __restrict__ WTs,
    const float* __restrict__ bias0, const float* __restrict__ bias1,
    int splitc, _Float16* __restrict__ C, int M) {
  __shared__ _Float16 bsm[64 * 256];   // 32 KB B chunk (swizzled rows)
  const int t = threadIdx.x;
  const int wave = t >> 6, lane = t & 63;
  const int l15 = lane & 15, quad = lane >> 4;
  const int m0 = blockIdx.x * 128 + wave * 32;
  const int nlo = blockIdx.y * (NC / NYS);
  const int nchunks = (NC / NYS) / 64;

  const _Float16* src = WTs + (size_t)nlo * 256;

  // ---- issue chunk-0 B loads first (latency covered by A load+convert) ----
  half8 pb[8];
  #pragma unroll
  for (int i = 0; i < 8; ++i)
    pb[i] = *(const half8*)(src + t * 8 + i * 2048);

  // ---- load + convert the wave's A slice (32 rows x 256) ----
  half8 a[2][8];
  #pragma unroll
  for (int i = 0; i < 2; ++i) {
    const float* Ar = A + (size_t)min(m0 + 16 * i + l15, M - 1) * 256 + quad * 8;
    #pragma unroll
    for (int ks = 0; ks < 8; ++ks) {
      const float4 f0 = *(const float4*)(Ar + ks * 32);
      const float4 f1 = *(const float4*)(Ar + ks * 32 + 4);
      a[i][ks][0] = (_Float16)f0.x; a[i][ks][1] = (_Float16)f0.y;
      a[i][ks][2] = (_Float16)f0.z; a[i][ks][3] = (_Float16)f0.w;
      a[i][ks][4] = (_Float16)f1.x; a[i][ks][5] = (_Float16)f1.y;
      a[i][ks][6] = (_Float16)f1.z; a[i][ks][7] = (_Float16)f1.w;
    }
  }

  #pragma unroll
  for (int i = 0; i < 8; ++i)
    *(half8*)&bsm[t * 8 + i * 2048] = pb[i];
  __syncthreads();

  for (int ch = 0; ch < nchunks; ++ch) {
    // prefetch next chunk into registers (overlaps with compute below)
    if (ch + 1 < nchunks) {
      const _Float16* s2 = src + (size_t)(ch + 1) * 64 * 256;
      #pragma unroll
      for (int i = 0; i < 8; ++i)
        pb[i] = *(const half8*)(s2 + t * 8 + i * 2048);
    }

    floatx4 acc[2][4] = {};
    #pragma unroll
    for (int ks = 0; ks < 8; ++ks) {
      half8 b[4];
      #pragma unroll
      for (int j = 0; j < 4; ++j)
        b[j] = *(const half8*)&bsm[(16 * j + l15) * 256 +
                                   ((((ks * 4 + quad) ^ (l15 & 7))) << 3)];
      if constexpr (SWZ) {
        #pragma unroll
        for (int j = 0; j < 4; ++j)
          #pragma unroll
          for (int i = 0; i < 2; ++i)
            acc[i][j] = __builtin_amdgcn_mfma_f32_16x16x32_f16(b[j], a[i][ks], acc[i][j], 0, 0, 0);
      } else {
        #pragma unroll
        for (int j = 0; j < 4; ++j)
          #pragma unroll
          for (int i = 0; i < 2; ++i)
            acc[i][j] = __builtin_amdgcn_mfma_f32_16x16x32_f16(a[i][ks], b[j], acc[i][j], 0, 0, 0);
      }
    }

    const int nc0 = nlo + ch * 64;

    if constexpr (SWZ) {
      #pragma unroll
      for (int j = 0; j < 4; ++j) {
        const int col0 = nc0 + 16 * j + quad * 4;
        const int h = col0 >> 5, c0 = col0 & 31;
        const float4 bq = *(const float4*)(bias0 + col0);
        #pragma unroll
        for (int i = 0; i < 2; ++i) {
          const int row = m0 + 16 * i + l15;
          if (row < M) {
            const int b = row / S_TOTAL;
            const int s = row - b * S_TOTAL;
            half4v pk;
            pk[0] = (_Float16)(acc[i][j][0] + bq.x);
            pk[1] = (_Float16)(acc[i][j][1] + bq.y);
            pk[2] = (_Float16)(acc[i][j][2] + bq.z);
            pk[3] = (_Float16)(acc[i][j][3] + bq.w);
            *(half4v*)(C + ((((size_t)b * NH + h) * S_TOTAL + s) * 32 + c0)) = pk;
          }
        }
      }
    } else {
      float bc[4];
      #pragma unroll
      for (int j = 0; j < 4; ++j) {
        const int col = nc0 + 16 * j + l15;
        bc[j] = (col < splitc) ? bias0[col] : bias1[col - splitc];
      }
      #pragma unroll
      for (int i = 0; i < 2; ++i) {
        #pragma unroll
        for (int r = 0; r < 4; ++r) {
          const int row = m0 + 16 * i + quad * 4 + r;
          if (row < M) {
            #pragma unroll
            for (int j = 0; j < 4; ++j)
              C[(size_t)row * NC + nc0 + 16 * j + l15] =
                  (_Float16)(acc[i][j][r] + bc[j]);
          }
        }
      }
    }

    __syncthreads();               // all waves done reading bsm
    if (ch + 1 < nchunks) {
      #pragma unroll
      for (int i = 0; i < 8; ++i)
        *(half8*)&bsm[t * 8 + i * 2048] = pb[i];
      __syncthreads();
    }
  }
}

// ---------------------------------------------------------------------------
// Fused softmax + deformable bilinear sampling. vproj [B,H,S,32].
//
// Round-13: PERSISTENT BLOCKS. Evidence r8/r11: per-block latency ~6us for
// ~400 insts -> block-latency-bound; occupancy stuck at 64% (20/32 waves/CU)
// with nothing static limiting (VGPR 40, LDS 6KB) -> the 40000-tiny-block
// launch rate starves residency. Fix: 2048 blocks (exactly 8/CU = 32
// waves/CU), each grid-striding ~20 queries with the UNCHANGED r8 per-query
// body (bit-identical numerics). Batch stays XCD-pinned (b = blk&3, mod-8
// XCD round-robin preserved). r10/r12 lessons: do NOT touch the phase-2
// load/FMA interleave — the compiler's 8-deep schedule beats forced MLP.
// ---------------------------------------------------------------------------
__global__ __launch_bounds__(256, 8) void msda_sample(
    const _Float16* __restrict__ vproj,     // [B,H,S,32] f16 (+guards)
    const _Float16* __restrict__ fused,     // [B*Q, 768] f16: off(512)|logit(256)
    const float* __restrict__ ref,          // [B*Q, 4, 2] f32
    float* __restrict__ out) {              // [B*Q, 256] f32
  const int lvl_h[NL] = {92, 46, 23, 12};
  const int lvl_w[NL] = {160, 80, 40, 20};
  const int lvl_s[NL] = {0, 14720, 18400, 19320};

  __shared__ int   addr_s[512];   // [(h*32+lp)*2 + rp]
  __shared__ float w2_s[1024];    // [side*512 + (h*32+lp)*2 + rp]

  const int t   = threadIdx.x;
  const int blk = blockIdx.x;      // 0..2047
  const int b   = blk & 3;         // pins batch to XCD (blk%8 round-robin)
  const int w   = blk >> 2;        // 0..511: within-batch block slot

  // ---- loop-invariant lane decomposition ----
  const int h  = t >> 5;
  const int lp = t & 31;
  const int l  = lp >> 3;
  const int p  = lp & 7;
  const int z  = p & 3;                      // NP=8 split (2,4): z = p % 4
  const int Wl = lvl_w[l], Hl = lvl_h[l], st = lvl_s[l];
  const int bh    = b * NH + h;
  const int lbase = bh * S_TOTAL + st;

  const int g  = t & 31;
  const int c  = g & 7;           // channel quad: channels 4c..4c+3
  const int sd = (g >> 3) & 1;    // 0 = left corner, 1 = right corner
  const int ph = g >> 4;          // point parity
  const int ldoff = sd * 32 + 4 * c;
  const int wbase = sd << 9;

  for (int q = w; q < NQ; q += 512) {
    const int row = b * NQ + q;

    // ---- softmax over the 32 (l,p) logits of this head (xor shuffles) ----
    const float logit = (float)fused[(size_t)row * 768 + 512 + t];
    float mxv = logit;
    #pragma unroll
    for (int m = 1; m < 32; m <<= 1) mxv = fmaxf(mxv, __shfl_xor(mxv, m));
    const float e = __expf(logit - mxv);
    float sum = e;
    #pragma unroll
    for (int m = 1; m < 32; m <<= 1) sum += __shfl_xor(sum, m);
    const float attnw = e / sum;

    // ---- location & bilinear setup ----
    const half2v o2 = *(const half2v*)(fused + (size_t)row * 768 + 2 * t);
    const float ox = (float)o2[0], oy = (float)o2[1];
    const float rx = ref[((size_t)row * 4 + z) * 2 + 0];
    const float ry = ref[((size_t)row * 4 + z) * 2 + 1];

    const float px = fmaf(rx, (float)Wl, ox) - 0.5f;
    const float py = fmaf(ry, (float)Hl, oy) - 0.5f;
    const float x0f = floorf(px), y0f = floorf(py);
    const float wx = px - x0f, wy = py - y0f;
    const int x0 = (int)x0f, y0 = (int)y0f;
    const int x1 = x0 + 1,   y1 = y0 + 1;

    // x: one 128B segment based at xb covers slots xb (left) and xb+1 (right)
    const float mx0 = (x0 >= 0 && x0 < Wl) ? 1.f : 0.f;
    const float mx1 = (x1 >= 0 && x1 < Wl) ? 1.f : 0.f;
    const float my0 = (y0 >= 0 && y0 < Hl) ? 1.f : 0.f;
    const float my1 = (y1 >= 0 && y1 < Hl) ? 1.f : 0.f;
    const int xb  = min(max(x0, -1), Wl - 1);        // guard pages cover x=-1/W
    const int cy0 = min(max(y0, 0), Hl - 1);
    const int cy1 = min(max(y1, 0), Hl - 1);

    const float wlc = attnw * (1.f - wx) * mx0;
    const float wrc = attnw * wx * mx1;

    addr_s[2 * t + 0] = (lbase + cy0 * Wl + xb) * 32;
    addr_s[2 * t + 1] = (lbase + cy1 * Wl + xb) * 32;
    w2_s[2 * t + 0]       = wlc * (1.f - wy) * my0;   // left,  top row
    w2_s[2 * t + 1]       = wlc * wy * my1;           // left,  bottom row
    w2_s[512 + 2 * t + 0] = wrc * (1.f - wy) * my0;   // right, top row
    w2_s[512 + 2 * t + 1] = wrc * wy * my1;           // right, bottom row
    __syncthreads();

    // ---- phase 2: lane g = (ph, side, chquad) within head group ----
    // load everything first (compiler schedules ~8-deep), then fma
    half4v vt[16], vb[16];
    float wt[16], wb[16];
    #pragma unroll
    for (int i = 0; i < 16; ++i) {
      const int idx = ((h << 5) + 2 * i + ph) * 2;
      const int at = addr_s[idx], ab = addr_s[idx + 1];
      wt[i] = w2_s[wbase + idx];
      wb[i] = w2_s[wbase + idx + 1];
      vt[i] = *(const half4v*)(vproj + at + ldoff);
      vb[i] = *(const half4v*)(vproj + ab + ldoff);
    }

    float a0 = 0.f, a1 = 0.f, a2 = 0.f, a3 = 0.f;
    #pragma unroll
    for (int i = 0; i < 16; ++i) {
      a0 = fmaf(wt[i], (float)vt[i][0], a0); a1 = fmaf(wt[i], (float)vt[i][1], a1);
      a2 = fmaf(wt[i], (float)vt[i][2], a2); a3 = fmaf(wt[i], (float)vt[i][3], a3);
      a0 = fmaf(wb[i], (float)vb[i][0], a0); a1 = fmaf(wb[i], (float)vb[i][1], a1);
      a2 = fmaf(wb[i], (float)vb[i][2], a2); a3 = fmaf(wb[i], (float)vb[i][3], a3);
    }

    // reduce over side (xor 8) and point parity (xor 16)
    a0 += __shfl_xor(a0, 8);  a1 += __shfl_xor(a1, 8);
    a2 += __shfl_xor(a2, 8);  a3 += __shfl_xor(a3, 8);
    a0 += __shfl_xor(a0, 16); a1 += __shfl_xor(a1, 16);
    a2 += __shfl_xor(a2, 16); a3 += __shfl_xor(a3, 16);

    if (g < 8) {    // sd==0 && ph==0: 8 lanes own the 8 channel quads
      float4 o; o.x = a0; o.y = a1; o.z = a2; o.w = a3;
      *(float4*)(out + (size_t)row * 256 + (h << 5) + 4 * c) = o;
    }
    __syncthreads();   // protect addr_s/w2_s before next iteration overwrites
  }
}

extern "C" void kernel_launch(void* const* d_in, const int* in_sizes, int n_in,
                              void* d_out, int out_size, void* d_ws, size_t ws_size,
                              hipStream_t stream) {
  const float* query  = (const float*)d_in[0];  // [4,10000,256]
  const float* value  = (const float*)d_in[1];  // [4,19560,256]
  const float* refpts = (const float*)d_in[2];  // [4,10000,4,2]
  const float* w_off  = (const float*)d_in[3];  // [256,512]
  const float* b_off  = (const float*)d_in[4];  // [512]
  const float* w_attn = (const float*)d_in[5];  // [256,256]
  const float* b_attn = (const float*)d_in[6];  // [256]
  const float* w_val  = (const float*)d_in[7];  // [256,256]
  const float* b_val  = (const float*)d_in[8];  // [256]
  float* out = (float*)d_out;

  // workspace layout (16B-multiple segments; 256B guards around vh for the
  // x=-1 / x=W edge reads, whose weights are zero)
  char* p = (char*)d_ws;
  p += 256;                                                         // front guard
  _Float16* vh    = (_Float16*)p;  p += (size_t)VROWS * 256 * 2;    // 40.1 MB
  p += 256;                                                         // back guard
  _Float16* wT768 = (_Float16*)p;  p += (size_t)768 * 256 * 2;      // swizzled
  _Float16* wvaT  = (_Float16*)p;  p += (size_t)256 * 256 * 2;      // swizzled
  _Float16* fused_h = (_Float16*)p; p += (size_t)NROW * 768 * 2;    // 61.4 MB

  // prep: all weight transposes in one launch
  prep_weights<<<1024, 256, 0, stream>>>(w_off, w_attn, w_val, wT768, wvaT);

  // GEMMs: A register-resident, B chunks via LDS, register-prefetch dbuf.
  // v = value@w_val -> [B,H,S,32] swizzled (coalesced half4 stores);
  // fused = query@[w_off|w_attn]
  gemm6<256, 1, true><<<dim3((VROWS + 127) / 128, 1), 256, 0, stream>>>(
      value, wvaT, b_val, b_val, 1 << 30, vh, VROWS);
  gemm6<768, 2, false><<<dim3((NROW + 127) / 128, 2), 256, 0, stream>>>(
      query, wT768, b_off, b_attn, 512, fused_h, NROW);

  // softmax + sample + weighted sum: persistent blocks, 8/CU = 32 waves/CU
  msda_sample<<<dim3(2048), 256, 0, stream>>>(vh, fused_h, refpts, out);
}

// Round 6
// 394.326 us; speedup vs baseline: 1.1368x; 1.1368x over previous
//
#include <hip/hip_runtime.h>

// Problem constants (fixed by setup_inputs)
#define BATCH    4
#define NQ       10000
#define EMB      256
#define NH       8
#define DH       32
#define NL       4
#define NP       8
#define S_TOTAL  19560
#define NROW     (BATCH * NQ)          // 40000
#define VROWS    (BATCH * S_TOTAL)     // 78240

typedef _Float16 half8 __attribute__((ext_vector_type(8)));
typedef _Float16 half4v __attribute__((ext_vector_type(4)));
typedef _Float16 half2v __attribute__((ext_vector_type(2)));
typedef float floatx4 __attribute__((ext_vector_type(4)));

// ---------------------------------------------------------------------------
// One-shot weight prep: transpose+swizzle all three weight matrices to f16.
// Logical row n (0..1023): [0,512) w_off -> wT768, [512,768) w_attn -> wT768,
// [768,1024) w_val (256 rows) -> wvaT. Swizzle: 16B chunk c of row n lands at
// chunk c ^ (n&7).
// ---------------------------------------------------------------------------
__global__ __launch_bounds__(256) void prep_weights(
    const float* __restrict__ w_off, const float* __restrict__ w_attn,
    const float* __restrict__ w_val, _Float16* __restrict__ wT768,
    _Float16* __restrict__ wvaT) {
  const int tid = blockIdx.x * 256 + threadIdx.x;   // over 1024*256
  const int n = tid >> 8, k = tid & 255;
  const int c = k >> 3, e = k & 7;
  const int swz = ((c ^ (n & 7)) << 3) + e;
  float v;
  _Float16* dst;
  if (n < 512)      { v = w_off[(size_t)k * 512 + n];          dst = wT768 + (size_t)n * 256; }
  else if (n < 768) { v = w_attn[(size_t)k * 256 + (n - 512)]; dst = wT768 + (size_t)n * 256; }
  else              { v = w_val[(size_t)k * 256 + (n - 768)];  dst = wvaT + (size_t)(n - 768) * 256; }
  dst[swz] = (_Float16)v;
}

// ---------------------------------------------------------------------------
// MFMA GEMM body (device fn): A-register-resident + B-chunk-in-LDS.
//   C = A[M,256]_f32 @ WTs[NC,256]^T + bias(col-select)
// Register-prefetch double-buffer; SWZ path uses swapped-operand MFMA so the
// 4 acc regs land on 4 consecutive channels -> coalesced 8B half4 stores.
// Round-14: both GEMMs merged into ONE launch (branch on blockIdx) — removes
// a launch gap and lets them co-fill the machine.
// ---------------------------------------------------------------------------
template <int NC, int NYS, bool SWZ>
__device__ __forceinline__ void gemm_body(
    const float* __restrict__ A, const _Float16* __restrict__ WTs,
    const float* __restrict__ bias0, const float* __restrict__ bias1,
    int splitc, _Float16* __restrict__ C, int M, int bx, int by,
    _Float16* bsm /* 64*256 LDS */) {
  const int t = threadIdx.x;
  const int wave = t >> 6, lane = t & 63;
  const int l15 = lane & 15, quad = lane >> 4;
  const int m0 = bx * 128 + wave * 32;
  const int nlo = by * (NC / NYS);
  const int nchunks = (NC / NYS) / 64;

  const _Float16* src = WTs + (size_t)nlo * 256;

  // ---- issue chunk-0 B loads first (latency covered by A load+convert) ----
  half8 pb[8];
  #pragma unroll
  for (int i = 0; i < 8; ++i)
    pb[i] = *(const half8*)(src + t * 8 + i * 2048);

  // ---- load + convert the wave's A slice (32 rows x 256) ----
  half8 a[2][8];
  #pragma unroll
  for (int i = 0; i < 2; ++i) {
    const float* Ar = A + (size_t)min(m0 + 16 * i + l15, M - 1) * 256 + quad * 8;
    #pragma unroll
    for (int ks = 0; ks < 8; ++ks) {
      const float4 f0 = *(const float4*)(Ar + ks * 32);
      const float4 f1 = *(const float4*)(Ar + ks * 32 + 4);
      a[i][ks][0] = (_Float16)f0.x; a[i][ks][1] = (_Float16)f0.y;
      a[i][ks][2] = (_Float16)f0.z; a[i][ks][3] = (_Float16)f0.w;
      a[i][ks][4] = (_Float16)f1.x; a[i][ks][5] = (_Float16)f1.y;
      a[i][ks][6] = (_Float16)f1.z; a[i][ks][7] = (_Float16)f1.w;
    }
  }

  #pragma unroll
  for (int i = 0; i < 8; ++i)
    *(half8*)&bsm[t * 8 + i * 2048] = pb[i];
  __syncthreads();

  for (int ch = 0; ch < nchunks; ++ch) {
    // prefetch next chunk into registers (overlaps with compute below)
    if (ch + 1 < nchunks) {
      const _Float16* s2 = src + (size_t)(ch + 1) * 64 * 256;
      #pragma unroll
      for (int i = 0; i < 8; ++i)
        pb[i] = *(const half8*)(s2 + t * 8 + i * 2048);
    }

    floatx4 acc[2][4] = {};
    #pragma unroll
    for (int ks = 0; ks < 8; ++ks) {
      half8 b[4];
      #pragma unroll
      for (int j = 0; j < 4; ++j)
        b[j] = *(const half8*)&bsm[(16 * j + l15) * 256 +
                                   ((((ks * 4 + quad) ^ (l15 & 7))) << 3)];
      if constexpr (SWZ) {
        #pragma unroll
        for (int j = 0; j < 4; ++j)
          #pragma unroll
          for (int i = 0; i < 2; ++i)
            acc[i][j] = __builtin_amdgcn_mfma_f32_16x16x32_f16(b[j], a[i][ks], acc[i][j], 0, 0, 0);
      } else {
        #pragma unroll
        for (int j = 0; j < 4; ++j)
          #pragma unroll
          for (int i = 0; i < 2; ++i)
            acc[i][j] = __builtin_amdgcn_mfma_f32_16x16x32_f16(a[i][ks], b[j], acc[i][j], 0, 0, 0);
      }
    }

    const int nc0 = nlo + ch * 64;

    if constexpr (SWZ) {
      #pragma unroll
      for (int j = 0; j < 4; ++j) {
        const int col0 = nc0 + 16 * j + quad * 4;
        const int h = col0 >> 5, c0 = col0 & 31;
        const float4 bq = *(const float4*)(bias0 + col0);
        #pragma unroll
        for (int i = 0; i < 2; ++i) {
          const int row = m0 + 16 * i + l15;
          if (row < M) {
            const int b = row / S_TOTAL;
            const int s = row - b * S_TOTAL;
            half4v pk;
            pk[0] = (_Float16)(acc[i][j][0] + bq.x);
            pk[1] = (_Float16)(acc[i][j][1] + bq.y);
            pk[2] = (_Float16)(acc[i][j][2] + bq.z);
            pk[3] = (_Float16)(acc[i][j][3] + bq.w);
            *(half4v*)(C + ((((size_t)b * NH + h) * S_TOTAL + s) * 32 + c0)) = pk;
          }
        }
      }
    } else {
      float bc[4];
      #pragma unroll
      for (int j = 0; j < 4; ++j) {
        const int col = nc0 + 16 * j + l15;
        bc[j] = (col < splitc) ? bias0[col] : bias1[col - splitc];
      }
      #pragma unroll
      for (int i = 0; i < 2; ++i) {
        #pragma unroll
        for (int r = 0; r < 4; ++r) {
          const int row = m0 + 16 * i + quad * 4 + r;
          if (row < M) {
            #pragma unroll
            for (int j = 0; j < 4; ++j)
              C[(size_t)row * NC + nc0 + 16 * j + l15] =
                  (_Float16)(acc[i][j][r] + bc[j]);
          }
        }
      }
    }

    __syncthreads();               // all waves done reading bsm
    if (ch + 1 < nchunks) {
      #pragma unroll
      for (int i = 0; i < 8; ++i)
        *(half8*)&bsm[t * 8 + i * 2048] = pb[i];
      __syncthreads();
    }
  }
}

#define VH_BLOCKS 612   // (78240+127)/128
#define FU_BLOCKS 313   // (40000+127)/128

__global__ __launch_bounds__(256, 3) void gemm_merged(
    const float* __restrict__ value, const float* __restrict__ query,
    const _Float16* __restrict__ wvaT, const _Float16* __restrict__ wT768,
    const float* __restrict__ b_val, const float* __restrict__ b_off,
    const float* __restrict__ b_attn,
    _Float16* __restrict__ vh, _Float16* __restrict__ fused_h) {
  __shared__ _Float16 bsm[64 * 256];   // 32 KB B chunk (swizzled rows)
  const int bid = blockIdx.x;
  if (bid < VH_BLOCKS) {
    gemm_body<256, 1, true>(value, wvaT, b_val, b_val, 1 << 30, vh, VROWS,
                            bid, 0, bsm);
  } else {
    const int r = bid - VH_BLOCKS;
    const int by = (r >= FU_BLOCKS) ? 1 : 0;
    const int bx = r - by * FU_BLOCKS;
    gemm_body<768, 2, false>(query, wT768, b_off, b_attn, 512, fused_h, NROW,
                             bx, by, bsm);
  }
}

// ---------------------------------------------------------------------------
// Fused softmax + deformable bilinear sampling. vproj [B,H,S,32].
//
// Round-14: r8 schedule (195.8us, 4x verified) + two issue-count cuts:
//   * 16B gathers in the 256-thread geometry: lane = (chunk c3, row rw,
//     parity pg); VMEM insts 32->16, addr VALU halved, LDS addr reads
//     32->16. FMA count unchanged. (r9's 16B attempt lost to its REDUNDANT
//     512-thread phase 1, not to the load width.)
//   * SADDR addressing: offsets biased +64 elems (covers x=-1 guard) stored
//     as uint32; loads become uniform_base + u32 voffset -> no per-load
//     64-bit VGPR address pair (~64 VALU ops/thread saved).
// Phase 1, schedule style (load-all arrays then fma), grid 40000 unchanged.
// ---------------------------------------------------------------------------
__global__ __launch_bounds__(256, 4) void msda_sample(
    const _Float16* __restrict__ vproj,     // [B,H,S,32] f16 (+guards)
    const _Float16* __restrict__ fused,     // [B*Q, 768] f16: off(512)|logit(256)
    const float* __restrict__ ref,          // [B*Q, 4, 2] f32
    float* __restrict__ out) {              // [B*Q, 256] f32
  const int lvl_h[NL] = {92, 46, 23, 12};
  const int lvl_w[NL] = {160, 80, 40, 20};
  const int lvl_s[NL] = {0, 14720, 18400, 19320};

  __shared__ int   addr_s[512];   // [(h*32+lp)*2 + rw], +64-elem biased
  __shared__ float w2_s[1024];    // [side*512 + (h*32+lp)*2 + rw]

  const int t   = threadIdx.x;
  const int blk = blockIdx.x;
  const int b   = blk & 3;             // pins batch to XCD (blk%8 round-robin)
  const int q   = blk >> 2;
  const int row = b * NQ + q;

  const int h  = t >> 5;
  const int lp = t & 31;
  const int l  = lp >> 3;
  const int p  = lp & 7;

  // ---- softmax over the 32 (l,p) logits of this head (xor shuffles) ----
  const float logit = (float)fused[(size_t)row * 768 + 512 + t];
  float mxv = logit;
  #pragma unroll
  for (int m = 1; m < 32; m <<= 1) mxv = fmaxf(mxv, __shfl_xor(mxv, m));
  const float e = __expf(logit - mxv);
  float sum = e;
  #pragma unroll
  for (int m = 1; m < 32; m <<= 1) sum += __shfl_xor(sum, m);
  const float attnw = e / sum;

  // ---- location & bilinear setup ----
  const half2v o2 = *(const half2v*)(fused + (size_t)row * 768 + 2 * t);
  const float ox = (float)o2[0], oy = (float)o2[1];
  const int z = p & 3;                       // NP=8 split (2,4): z = p % 4
  const float rx = ref[((size_t)row * 4 + z) * 2 + 0];
  const float ry = ref[((size_t)row * 4 + z) * 2 + 1];
  const int Wl = lvl_w[l], Hl = lvl_h[l], st = lvl_s[l];

  const float px = fmaf(rx, (float)Wl, ox) - 0.5f;
  const float py = fmaf(ry, (float)Hl, oy) - 0.5f;
  const float x0f = floorf(px), y0f = floorf(py);
  const float wx = px - x0f, wy = py - y0f;
  const int x0 = (int)x0f, y0 = (int)y0f;
  const int x1 = x0 + 1,   y1 = y0 + 1;

  // x: one 128B segment based at xb covers slots xb (left) and xb+1 (right)
  const float mx0 = (x0 >= 0 && x0 < Wl) ? 1.f : 0.f;
  const float mx1 = (x1 >= 0 && x1 < Wl) ? 1.f : 0.f;
  const float my0 = (y0 >= 0 && y0 < Hl) ? 1.f : 0.f;
  const float my1 = (y1 >= 0 && y1 < Hl) ? 1.f : 0.f;
  const int xb  = min(max(x0, -1), Wl - 1);          // guard pages cover x=-1/W
  const int cy0 = min(max(y0, 0), Hl - 1);
  const int cy1 = min(max(y1, 0), Hl - 1);

  const int bh   = b * NH + h;
  const int lbase = bh * S_TOTAL + st;
  const float wlc = attnw * (1.f - wx) * mx0;
  const float wrc = attnw * wx * mx1;

  addr_s[2 * t + 0] = (lbase + cy0 * Wl + xb) * 32 + 64;
  addr_s[2 * t + 1] = (lbase + cy1 * Wl + xb) * 32 + 64;
  w2_s[2 * t + 0]       = wlc * (1.f - wy) * my0;   // left,  top row
  w2_s[2 * t + 1]       = wlc * wy * my1;           // left,  bottom row
  w2_s[512 + 2 * t + 0] = wrc * (1.f - wy) * my0;   // right, top row
  w2_s[512 + 2 * t + 1] = wrc * wy * my1;           // right, bottom row
  __syncthreads();

  // ---- phase 2: lane g = (pg, rw, c3) within head group ----
  // c3 = 16B chunk of the 128B row (sd = c3>>2, channel oct o = c3&3);
  // rw = top/bottom row; pg = lp parity.
  const int g  = t & 31;
  const int c3 = g & 7;
  const int rw = (g >> 3) & 1;
  const int pg = g >> 4;
  const uint32_t coff = (uint32_t)(c3 << 3);
  const int wsd = (c3 >> 2) << 9;
  const _Float16* vbase = vproj - 64;   // cancels the +64 offset bias

  // load everything first (compiler schedules ~8-deep), then fma
  half8 v[16];
  float w[16];
  #pragma unroll
  for (int i = 0; i < 16; ++i) {
    const int idx = (((h << 5) + 2 * i + pg) << 1) + rw;
    w[i] = w2_s[wsd + idx];
    v[i] = *(const half8*)(vbase + ((uint32_t)addr_s[idx] + coff));
  }

  float a0 = 0.f, a1 = 0.f, a2 = 0.f, a3 = 0.f;
  float a4 = 0.f, a5 = 0.f, a6 = 0.f, a7 = 0.f;
  #pragma unroll
  for (int i = 0; i < 16; ++i) {
    a0 = fmaf(w[i], (float)v[i][0], a0); a1 = fmaf(w[i], (float)v[i][1], a1);
    a2 = fmaf(w[i], (float)v[i][2], a2); a3 = fmaf(w[i], (float)v[i][3], a3);
    a4 = fmaf(w[i], (float)v[i][4], a4); a5 = fmaf(w[i], (float)v[i][5], a5);
    a6 = fmaf(w[i], (float)v[i][6], a6); a7 = fmaf(w[i], (float)v[i][7], a7);
  }

  // reduce over side (xor 4), row (xor 8), parity (xor 16)
  #pragma unroll
  for (int m = 4; m <= 16; m <<= 1) {
    a0 += __shfl_xor(a0, m); a1 += __shfl_xor(a1, m);
    a2 += __shfl_xor(a2, m); a3 += __shfl_xor(a3, m);
    a4 += __shfl_xor(a4, m); a5 += __shfl_xor(a5, m);
    a6 += __shfl_xor(a6, m); a7 += __shfl_xor(a7, m);
  }

  if (g < 4) {    // sd==0, rw==0, pg==0: 4 lanes own the 4 channel octs
    float* op = out + (size_t)row * 256 + (h << 5) + (g << 3);
    float4 o0; o0.x = a0; o0.y = a1; o0.z = a2; o0.w = a3;
    float4 o1; o1.x = a4; o1.y = a5; o1.z = a6; o1.w = a7;
    *(float4*)op = o0;
    *(float4*)(op + 4) = o1;
  }
}

extern "C" void kernel_launch(void* const* d_in, const int* in_sizes, int n_in,
                              void* d_out, int out_size, void* d_ws, size_t ws_size,
                              hipStream_t stream) {
  const float* query  = (const float*)d_in[0];  // [4,10000,256]
  const float* value  = (const float*)d_in[1];  // [4,19560,256]
  const float* refpts = (const float*)d_in[2];  // [4,10000,4,2]
  const float* w_off  = (const float*)d_in[3];  // [256,512]
  const float* b_off  = (const float*)d_in[4];  // [512]
  const float* w_attn = (const float*)d_in[5];  // [256,256]
  const float* b_attn = (const float*)d_in[6];  // [256]
  const float* w_val  = (const float*)d_in[7];  // [256,256]
  const float* b_val  = (const float*)d_in[8];  // [256]
  float* out = (float*)d_out;

  // workspace layout (16B-multiple segments; 256B guards around vh for the
  // x=-1 / x=W edge reads, whose weights are zero)
  char* p = (char*)d_ws;
  p += 256;                                                         // front guard
  _Float16* vh    = (_Float16*)p;  p += (size_t)VROWS * 256 * 2;    // 40.1 MB
  p += 256;                                                         // back guard
  _Float16* wT768 = (_Float16*)p;  p += (size_t)768 * 256 * 2;      // swizzled
  _Float16* wvaT  = (_Float16*)p;  p += (size_t)256 * 256 * 2;      // swizzled
  _Float16* fused_h = (_Float16*)p; p += (size_t)NROW * 768 * 2;    // 61.4 MB

  // prep: all weight transposes in one launch
  prep_weights<<<1024, 256, 0, stream>>>(w_off, w_attn, w_val, wT768, wvaT);

  // both GEMMs in ONE launch: vh blocks [0,612), fused blocks [612,1238)
  gemm_merged<<<dim3(VH_BLOCKS + 2 * FU_BLOCKS), 256, 0, stream>>>(
      value, query, wvaT, wT768, b_val, b_off, b_attn, vh, fused_h);

  // softmax + sample + weighted sum
  msda_sample<<<dim3(NROW), 256, 0, stream>>>(vh, fused_h, refpts, out);
}